// Round 6
// baseline (46499.539 us; speedup 1.0000x reference)
//
#include <hip/hip_runtime.h>
#include <math.h>

typedef _Float16 f16;
typedef f16 half8 __attribute__((ext_vector_type(8)));
typedef float f32x4 __attribute__((ext_vector_type(4)));

#define NBATCH 64
#define NTIME  512
#define NU     1024
#define NE     256
#define NVOCAB 32000
#define NA     16     // A-role WGs (z+r), 64 cols of each gate
#define NB     8      // B-role WGs (hh), 128 cols

// ---------------- ws layout (bytes) — total 8.4 MB (proven-safe < 17.4 MB) ----------------
#define OFF_RKT   0            // 3072*1024*2 = 6,291,456
#define OFF_KWT   6291456      // 3072*256*2  = 1,572,864
#define OFF_HF16  7864320      // 131,072
#define OFF_RH16  7995392      // 131,072
#define OFF_ZBUF  8126464      // 262,144
#define OFF_FLAGS 8388608      // 128

#define MFMA16 __builtin_amdgcn_mfma_f32_16x16x32_f16

__global__ void prep_kernel(const float* __restrict__ hid, f16* __restrict__ hf16,
                            int* __restrict__ flags)
{
    int stride = gridDim.x * blockDim.x;
    int t0 = blockIdx.x * blockDim.x + threadIdx.x;
    for (int i = t0; i < NBATCH * NU; i += stride) hf16[i] = (f16)hid[i];
    if (t0 < 32) flags[t0] = 0;
}

// Tiled transpose: src [R x 3072] f32 row-major  ->  dst [3072 x R] f16 row-major
__global__ void transpose_kernel(const float* __restrict__ src, f16* __restrict__ dst, int R)
{
    __shared__ f16 tile[64 * 65];
    int c0 = blockIdx.x * 64, r0 = blockIdx.y * 64;
    int cc = threadIdx.x & 63, rr = threadIdx.x >> 6;
#pragma unroll
    for (int l = 0; l < 16; ++l) {
        int r = rr + l * 4;
        tile[r * 65 + cc] = (f16)src[(size_t)(r0 + r) * 3072 + c0 + cc];
    }
    __syncthreads();
    int k = threadIdx.x & 63, c = threadIdx.x >> 6;
#pragma unroll
    for (int l = 0; l < 16; ++l) {
        int cL = c + l * 4;
        dst[(size_t)(c0 + cL) * R + r0 + k] = tile[k * 65 + cL];
    }
}

// ---- per-access coherent (MALL-level) ops: sc0 sc1 bypass non-coherent L1/L2 ----
__device__ __forceinline__ half8 ld_cc_b128(const f16* p) {
    half8 v;
    asm volatile("global_load_dwordx4 %0, %1, off sc0 sc1" : "=v"(v) : "v"(p));
    return v;
}
__device__ __forceinline__ unsigned ld_cc_u16(const f16* p) {
    unsigned v;
    asm volatile("global_load_ushort %0, %1, off sc0 sc1" : "=v"(v) : "v"(p));
    return v;
}
__device__ __forceinline__ float ld_cc_f32(const float* p) {
    float v;
    asm volatile("global_load_dword %0, %1, off sc0 sc1" : "=v"(v) : "v"(p));
    return v;
}
__device__ __forceinline__ void st_cc_f32(float* p, float v) {
    asm volatile("global_store_dword %0, %1, off sc0 sc1" :: "v"(p), "v"(v));
}
__device__ __forceinline__ void st_cc_u16(f16* p, unsigned v) {
    asm volatile("global_store_short %0, %1, off sc0 sc1" :: "v"(p), "v"(v));
}
__device__ __forceinline__ void st_cc_i32(int* p, int v) {
    asm volatile("global_store_dword %0, %1, off sc0 sc1" :: "v"(p), "v"(v));
}
__device__ __forceinline__ void drain_vm() {
    asm volatile("s_waitcnt vmcnt(0)" ::: "memory");
    __builtin_amdgcn_sched_barrier(0);   // rule #18
}
// load 8 consecutive f32 and convert to half8 (16B-aligned p)
__device__ __forceinline__ half8 cvt8(const float* p) {
    float4 u = *(const float4*)(p);
    float4 v = *(const float4*)(p + 4);
    half8 a;
    a[0] = (f16)u.x; a[1] = (f16)u.y; a[2] = (f16)u.z; a[3] = (f16)u.w;
    a[4] = (f16)v.x; a[5] = (f16)v.y; a[6] = (f16)v.z; a[7] = (f16)v.w;
    return a;
}

// 24 persistent WGs x 256 threads.
// wg [0,16) : A-role — z,r gates, cols [wg*64, wg*64+64) of each gate
// wg [16,24): B-role — hh + state update, cols [(wg-16)*128, +128)
__global__ __launch_bounds__(256, 1)
void scan_kernel(const int* __restrict__ x, const float* __restrict__ bias,
                 const float* __restrict__ emb, const f16* __restrict__ rkT,
                 const f16* __restrict__ kwT, const float* __restrict__ hid,
                 f16* __restrict__ hf16, f16* __restrict__ rh16, float* __restrict__ zbuf,
                 int* __restrict__ flags, float* __restrict__ out)
{
    const int wg = blockIdx.x, tid = threadIdx.x, lane = tid & 63, wv = tid >> 6;
    const int arow  = 16 * wv + (lane & 15);     // A-fragment row (batch)
    const int aoff  = 8 * (lane >> 4);           // k sub-offset within 32-chunk
    const int drow0 = 16 * wv + 4 * (lane >> 4); // D rows = drow0 + i
    const int c16   = lane & 15;

    int* aflags = flags;        // 16
    int* bflags = flags + NA;   // 8

    if (wg < NA) {
        // ---------------- A role: z and r, 64 cols each ----------------
        const int czb = wg * 64;
        const f16 *wz[4], *wr[4], *kz[4], *kr[4];
        float bz[4], br[4];
        int colz[4];
#pragma unroll
        for (int ct = 0; ct < 4; ++ct) {
            int gz = czb + ct * 16 + c16;
            int gr = 1024 + gz;
            colz[ct] = gz;
            bz[ct] = bias[gz]; br[ct] = bias[gr];
            wz[ct] = rkT + (size_t)gz * NU + aoff;
            wr[ct] = rkT + (size_t)gr * NU + aoff;
            kz[ct] = kwT + (size_t)gz * NE + aoff;
            kr[ct] = kwT + (size_t)gr * NE + aoff;
        }
        for (int t = 0; t < NTIME; ++t) {
            f32x4 az[4], ar[4];
#pragma unroll
            for (int ct = 0; ct < 4; ++ct) { az[ct] = f32x4{0,0,0,0}; ar[ct] = f32x4{0,0,0,0}; }
            // x-part (h-independent, overlaps producer phase): f32 emb -> f16 frags
            {
                const int xid = x[arow * NTIME + t];
                const float* ep = emb + (size_t)xid * NE + aoff;
                half8 ea[8];
#pragma unroll
                for (int kc = 0; kc < 8; ++kc) ea[kc] = cvt8(ep + kc * 32);
#pragma unroll
                for (int kc = 0; kc < 8; ++kc)
#pragma unroll
                    for (int ct = 0; ct < 4; ++ct) {
                        az[ct] = MFMA16(ea[kc], *(const half8*)(kz[ct] + kc * 32), az[ct], 0, 0, 0);
                        ar[ct] = MFMA16(ea[kc], *(const half8*)(kr[ct] + kc * 32), ar[ct], 0, 0, 0);
                    }
            }
            // wait: all B finished step t-1 (h_t visible; z/rh consumed)
            if (tid < 64) {
                for (;;) {
                    int v = __hip_atomic_load(&bflags[lane & 7], __ATOMIC_RELAXED, __HIP_MEMORY_SCOPE_AGENT);
                    if (__all(v >= t)) break;
                    __builtin_amdgcn_s_sleep(1);
                }
            }
            __syncthreads();
            __builtin_amdgcn_sched_barrier(0);

            // h A-fragments + own-col h values (coherent loads)
            const f16* hp = hf16 + arow * NU + aoff;
            half8 ha[32];
#pragma unroll
            for (int kc = 0; kc < 32; ++kc) ha[kc] = ld_cc_b128(hp + kc * 32);
            unsigned hs[16];
#pragma unroll
            for (int ct = 0; ct < 4; ++ct)
#pragma unroll
                for (int i = 0; i < 4; ++i)
                    hs[ct * 4 + i] = ld_cc_u16(hf16 + (size_t)(drow0 + i) * NU + colz[ct]);
            drain_vm();
#pragma unroll
            for (int kc = 0; kc < 32; ++kc)
#pragma unroll
                for (int ct = 0; ct < 4; ++ct) {
                    az[ct] = MFMA16(ha[kc], *(const half8*)(wz[ct] + kc * 32), az[ct], 0, 0, 0);
                    ar[ct] = MFMA16(ha[kc], *(const half8*)(wr[ct] + kc * 32), ar[ct], 0, 0, 0);
                }
            // gates + comm stores
#pragma unroll
            for (int ct = 0; ct < 4; ++ct)
#pragma unroll
                for (int i = 0; i < 4; ++i) {
                    int b = drow0 + i;
                    float z = 1.f / (1.f + exp2f(-1.4426950408889634f * (az[ct][i] + bz[ct])));
                    st_cc_f32(&zbuf[b * NU + colz[ct]], z);
                    float r = 1.f / (1.f + exp2f(-1.4426950408889634f * (ar[ct][i] + br[ct])));
                    union { unsigned short u; f16 h; } cv; cv.u = (unsigned short)hs[ct * 4 + i];
                    union { f16 h; unsigned short u; } cw; cw.h = (f16)(r * (float)cv.h);
                    st_cc_u16(&rh16[b * NU + colz[ct]], (unsigned)cw.u);
                }
            asm volatile("s_waitcnt vmcnt(0)" ::: "memory");
            __syncthreads();
            if (tid == 0) st_cc_i32(&aflags[wg], t + 1);
        }
    } else {
        // ---------------- B role: hh + state update, 128 cols ----------------
        const int j = wg - NA, chb = j * 128;
        const f16 *wh[8], *kh[8];
        float bh[8];
        int colh[8];
#pragma unroll
        for (int ct = 0; ct < 8; ++ct) {
            int gc = chb + ct * 16 + c16;          // hh column in [0,1024)
            colh[ct] = gc;
            bh[ct] = bias[2048 + gc];
            wh[ct] = rkT + (size_t)(2048 + gc) * NU + aoff;
            kh[ct] = kwT + (size_t)(2048 + gc) * NE + aoff;
        }
        float hprev[8][4];
#pragma unroll
        for (int ct = 0; ct < 8; ++ct)
#pragma unroll
            for (int i = 0; i < 4; ++i)
                hprev[ct][i] = hid[(size_t)(drow0 + i) * NU + colh[ct]];

        for (int t = 0; t < NTIME; ++t) {
            f32x4 ah[8];
#pragma unroll
            for (int ct = 0; ct < 8; ++ct) ah[ct] = f32x4{0,0,0,0};
            // x-part
            {
                const int xid = x[arow * NTIME + t];
                const float* ep = emb + (size_t)xid * NE + aoff;
                half8 ea[8];
#pragma unroll
                for (int kc = 0; kc < 8; ++kc) ea[kc] = cvt8(ep + kc * 32);
#pragma unroll
                for (int kc = 0; kc < 8; ++kc)
#pragma unroll
                    for (int ct = 0; ct < 8; ++ct)
                        ah[ct] = MFMA16(ea[kc], *(const half8*)(kh[ct] + kc * 32), ah[ct], 0, 0, 0);
            }
            // wait: all A finished step t (z/rh ready; h_t no longer read)
            if (tid < 64) {
                for (;;) {
                    int v = __hip_atomic_load(&aflags[lane & 15], __ATOMIC_RELAXED, __HIP_MEMORY_SCOPE_AGENT);
                    if (__all(v >= t + 1)) break;
                    __builtin_amdgcn_s_sleep(1);
                }
            }
            __syncthreads();
            __builtin_amdgcn_sched_barrier(0);

            const f16* rp = rh16 + arow * NU + aoff;
            half8 ra[32];
#pragma unroll
            for (int kc = 0; kc < 32; ++kc) ra[kc] = ld_cc_b128(rp + kc * 32);
            float zz[8][4];
#pragma unroll
            for (int ct = 0; ct < 8; ++ct)
#pragma unroll
                for (int i = 0; i < 4; ++i)
                    zz[ct][i] = ld_cc_f32(&zbuf[(size_t)(drow0 + i) * NU + colh[ct]]);
            drain_vm();
#pragma unroll
            for (int kc = 0; kc < 32; ++kc)
#pragma unroll
                for (int ct = 0; ct < 8; ++ct)
                    ah[ct] = MFMA16(ra[kc], *(const half8*)(wh[ct] + kc * 32), ah[ct], 0, 0, 0);
            // state update + h store (comm)
#pragma unroll
            for (int ct = 0; ct < 8; ++ct)
#pragma unroll
                for (int i = 0; i < 4; ++i) {
                    int b = drow0 + i;
                    float s = ah[ct][i] + bh[ct];
                    float e = exp2f(2.8853900817779268f * s);
                    float hh = 1.f - 2.f / (e + 1.f);          // tanh(s), inf-safe
                    float hn = zz[ct][i] * hprev[ct][i] + (1.f - zz[ct][i]) * hh;
                    hprev[ct][i] = hn;
                    union { f16 h; unsigned short u; } cw; cw.h = (f16)hn;
                    st_cc_u16(&hf16[b * NU + colh[ct]], (unsigned)cw.u);
                }
            asm volatile("s_waitcnt vmcnt(0)" ::: "memory");
            __syncthreads();
            if (tid == 0) st_cc_i32(&bflags[j], t + 1);
            // out stores AFTER the flag — acks overlap the A-phase
#pragma unroll
            for (int ct = 0; ct < 8; ++ct)
#pragma unroll
                for (int i = 0; i < 4; ++i) {
                    int b = drow0 + i;
                    __builtin_nontemporal_store(hprev[ct][i],
                        &out[(size_t)b * (NTIME * NU) + (size_t)t * NU + colh[ct]]);
                }
            if (t == NTIME - 1) {
#pragma unroll
                for (int ct = 0; ct < 8; ++ct)
#pragma unroll
                    for (int i = 0; i < 4; ++i)
                        __builtin_nontemporal_store(hprev[ct][i],
                            &out[(size_t)NBATCH * NTIME * NU + (drow0 + i) * NU + colh[ct]]);
            }
        }
    }
}

extern "C" void kernel_launch(void* const* d_in, const int* in_sizes, int n_in,
                              void* d_out, int out_size, void* d_ws, size_t ws_size,
                              hipStream_t stream)
{
    const int*   x    = (const int*)d_in[0];
    const float* hid  = (const float*)d_in[1];
    const float* emb  = (const float*)d_in[2];
    const float* kw   = (const float*)d_in[3];
    const float* rk   = (const float*)d_in[4];
    const float* bias = (const float*)d_in[5];

    char* ws = (char*)d_ws;
    f16*   rkT   = (f16*)  (ws + OFF_RKT);
    f16*   kwT   = (f16*)  (ws + OFF_KWT);
    f16*   hf16  = (f16*)  (ws + OFF_HF16);
    f16*   rh16  = (f16*)  (ws + OFF_RH16);
    float* zbuf  = (float*)(ws + OFF_ZBUF);
    int*   flags = (int*)  (ws + OFF_FLAGS);
    float* out   = (float*)d_out;

    prep_kernel<<<64, 256, 0, stream>>>(hid, hf16, flags);
    transpose_kernel<<<dim3(48, 16), 256, 0, stream>>>(rk, rkT, NU);   // rk: 1024 x 3072
    transpose_kernel<<<dim3(48, 4),  256, 0, stream>>>(kw, kwT, NE);   // kw:  256 x 3072
    scan_kernel<<<NA + NB, 256, 0, stream>>>(x, bias, emb, rkT, kwT, hid,
                                             hf16, rh16, zbuf, flags, out);
}

// Round 7
// 10937.272 us; speedup vs baseline: 4.2515x; 4.2515x over previous
//
#include <hip/hip_runtime.h>
#include <math.h>

typedef _Float16 f16;
typedef f16 half8 __attribute__((ext_vector_type(8)));
typedef float f32x4 __attribute__((ext_vector_type(4)));

#define NBATCH 64
#define NTIME  512
#define NU     1024
#define NE     256
#define NA     32     // A-role WGs: 32 z-cols + 32 r-cols each (Wz+Wr in LDS)
#define NB     16     // B-role WGs: 64 hh-cols each (Wh in LDS)

// ---------------- ws layout (bytes) — total ~2.1 MB ----------------
#define OFF_KWT   0            // 3072*256*2 = 1,572,864 (kernel^T, f16, [col][k])
#define OFF_HF16  1572864      // 131,072
#define OFF_RH16  1703936      // 131,072
#define OFF_ZBUF  1835008      // 262,144
#define OFF_FLAGS 2097152      // 192

#define MFMA16 __builtin_amdgcn_mfma_f32_16x16x32_f16

__global__ void prep_kernel(const float* __restrict__ hid, f16* __restrict__ hf16,
                            int* __restrict__ flags)
{
    int stride = gridDim.x * blockDim.x;
    int t0 = blockIdx.x * blockDim.x + threadIdx.x;
    for (int i = t0; i < NBATCH * NU; i += stride) hf16[i] = (f16)hid[i];
    if (t0 < 64) flags[t0] = 0;
}

// Tiled transpose: src [R x 3072] f32 row-major -> dst [3072 x R] f16 row-major
__global__ void transpose_kernel(const float* __restrict__ src, f16* __restrict__ dst, int R)
{
    __shared__ f16 tile[64 * 65];
    int c0 = blockIdx.x * 64, r0 = blockIdx.y * 64;
    int cc = threadIdx.x & 63, rr = threadIdx.x >> 6;
#pragma unroll
    for (int l = 0; l < 16; ++l) {
        int r = rr + l * 4;
        tile[r * 65 + cc] = (f16)src[(size_t)(r0 + r) * 3072 + c0 + cc];
    }
    __syncthreads();
    int k = threadIdx.x & 63, c = threadIdx.x >> 6;
#pragma unroll
    for (int l = 0; l < 16; ++l) {
        int cL = c + l * 4;
        dst[(size_t)(c0 + cL) * R + r0 + k] = tile[k * 65 + cL];
    }
}

// ---- per-access coherent (MALL-level) ops: sc0 sc1 bypass non-coherent L1/L2 ----
__device__ __forceinline__ half8 ld_cc_b128(const f16* p) {
    half8 v;
    asm volatile("global_load_dwordx4 %0, %1, off sc0 sc1" : "=v"(v) : "v"(p));
    return v;
}
__device__ __forceinline__ unsigned ld_cc_u16(const f16* p) {
    unsigned v;
    asm volatile("global_load_ushort %0, %1, off sc0 sc1" : "=v"(v) : "v"(p));
    return v;
}
__device__ __forceinline__ float ld_cc_f32(const float* p) {
    float v;
    asm volatile("global_load_dword %0, %1, off sc0 sc1" : "=v"(v) : "v"(p));
    return v;
}
__device__ __forceinline__ void st_cc_f32(float* p, float v) {
    asm volatile("global_store_dword %0, %1, off sc0 sc1" :: "v"(p), "v"(v));
}
__device__ __forceinline__ void st_cc_u16(f16* p, unsigned v) {
    asm volatile("global_store_short %0, %1, off sc0 sc1" :: "v"(p), "v"(v));
}
__device__ __forceinline__ void st_cc_i32(int* p, int v) {
    asm volatile("global_store_dword %0, %1, off sc0 sc1" :: "v"(p), "v"(v));
}
__device__ __forceinline__ void drain_vm() {
    asm volatile("s_waitcnt vmcnt(0)" ::: "memory");
    __builtin_amdgcn_sched_barrier(0);   // rule #18
}
// load 8 consecutive f32, convert to half8
__device__ __forceinline__ half8 cvt8(const float* p) {
    float4 u = *(const float4*)(p);
    float4 v = *(const float4*)(p + 4);
    half8 a;
    a[0] = (f16)u.x; a[1] = (f16)u.y; a[2] = (f16)u.z; a[3] = (f16)u.w;
    a[4] = (f16)v.x; a[5] = (f16)v.y; a[6] = (f16)v.z; a[7] = (f16)v.w;
    return a;
}

// 48 persistent WGs x 256 threads, 1 WG/CU.
// wg [0,32) : A-role — z,r gates, cols [wg*32, wg*32+32) of each gate
// wg [32,48): B-role — hh + state update, cols [(wg-32)*64, +64)
__global__ __launch_bounds__(256, 1)
void scan_kernel(const int* __restrict__ x, const float* __restrict__ rk,
                 const float* __restrict__ bias, const float* __restrict__ emb,
                 const f16* __restrict__ kwT, const float* __restrict__ hid,
                 f16* __restrict__ hf16, f16* __restrict__ rh16, float* __restrict__ zbuf,
                 int* __restrict__ flags, float* __restrict__ out)
{
    // 128 KiB static LDS (proven >64KB OK at 80KB in round 3; gfx950 HW max 160KB)
    __shared__ char lds[131072];

    const int wg = blockIdx.x, tid = threadIdx.x, lane = tid & 63, wv = tid >> 6;
    const bool isB = wg >= NA;
    const int arow  = 16 * wv + (lane & 15);     // A-fragment row (batch)
    const int aoff  = 8 * (lane >> 4);           // k sub-offset within 32-chunk
    const int drow0 = 16 * wv + 4 * (lane >> 4); // D rows = drow0 + i
    const int c16   = lane & 15;
    const int swz   = (c16 & 7) << 4;

    int* aflags = flags;        // 32
    int* bflags = flags + NA;   // 16

    // ---- one-time LDS weight staging from rk (f32 row-major [1024][3072]) ----
    if (!isB) {
        const int czb = wg * 32;
        for (int idx = tid; idx < 32 * 1024; idx += 256) {
            int c = idx & 31, k = idx >> 5, sw = (k * 2) ^ ((c & 7) << 4);
            *(f16*)(lds + c * 2048 + sw)         = (f16)rk[k * 3072 + czb + c];          // Wz
            *(f16*)(lds + 65536 + c * 2048 + sw) = (f16)rk[k * 3072 + 1024 + czb + c];   // Wr
        }
    } else {
        const int chb = (wg - NA) * 64;
        for (int idx = tid; idx < 64 * 1024; idx += 256) {
            int c = idx & 63, k = idx >> 6, sw = (k * 2) ^ ((c & 7) << 4);
            *(f16*)(lds + c * 2048 + sw) = (f16)rk[k * 3072 + 2048 + chb + c];           // Wh
        }
    }
    __syncthreads();

    if (!isB) {
        // ---------------- A role: z and r, 32 cols each ----------------
        const int czb = wg * 32;
        float bz[2], br[2];
        int colz[2];
        const f16 *kz[2], *kr[2];
#pragma unroll
        for (int ct = 0; ct < 2; ++ct) {
            int gz = czb + ct * 16 + c16;
            colz[ct] = gz;
            bz[ct] = bias[gz]; br[ct] = bias[1024 + gz];
            kz[ct] = kwT + (size_t)gz * NE + aoff;
            kr[ct] = kwT + (size_t)(1024 + gz) * NE + aoff;
        }
        for (int t = 0; t < NTIME; ++t) {
            f32x4 az[2], ar[2];
#pragma unroll
            for (int ct = 0; ct < 2; ++ct) { az[ct] = f32x4{0,0,0,0}; ar[ct] = f32x4{0,0,0,0}; }
            // x-part (h-independent, overlaps producer phase)
            {
                const int xid = x[arow * NTIME + t];
                const float* ep = emb + (size_t)xid * NE + aoff;
                half8 ea[8];
#pragma unroll
                for (int kc = 0; kc < 8; ++kc) ea[kc] = cvt8(ep + kc * 32);
#pragma unroll
                for (int kc = 0; kc < 8; ++kc)
#pragma unroll
                    for (int ct = 0; ct < 2; ++ct) {
                        az[ct] = MFMA16(ea[kc], *(const half8*)(kz[ct] + kc * 32), az[ct], 0, 0, 0);
                        ar[ct] = MFMA16(ea[kc], *(const half8*)(kr[ct] + kc * 32), ar[ct], 0, 0, 0);
                    }
            }
            // wait: all B finished step t-1 (h_t visible; old z/rh consumed)
            if (tid < 64) {
                for (;;) {
                    int v = __hip_atomic_load(&bflags[lane & 15], __ATOMIC_RELAXED, __HIP_MEMORY_SCOPE_AGENT);
                    if (__all(v >= t)) break;
                    __builtin_amdgcn_s_sleep(1);
                }
            }
            __syncthreads();
            __builtin_amdgcn_sched_barrier(0);

            // h A-fragments + own-col h (coherent)
            const f16* hp = hf16 + arow * NU + aoff;
            half8 ha[32];
#pragma unroll
            for (int kc = 0; kc < 32; ++kc) ha[kc] = ld_cc_b128(hp + kc * 32);
            unsigned hs[8];
#pragma unroll
            for (int ct = 0; ct < 2; ++ct)
#pragma unroll
                for (int i = 0; i < 4; ++i)
                    hs[ct * 4 + i] = ld_cc_u16(hf16 + (size_t)(drow0 + i) * NU + colz[ct]);
            drain_vm();
            // recurrent MFMA: B-operands from LDS (Wz @0, Wr @64K)
#pragma unroll
            for (int kc = 0; kc < 32; ++kc) {
                int kb = ((kc * 32 + aoff) * 2) ^ swz;
#pragma unroll
                for (int ct = 0; ct < 2; ++ct) {
                    az[ct] = MFMA16(ha[kc], *(const half8*)(lds + (ct * 16 + c16) * 2048 + kb), az[ct], 0, 0, 0);
                    ar[ct] = MFMA16(ha[kc], *(const half8*)(lds + 65536 + (ct * 16 + c16) * 2048 + kb), ar[ct], 0, 0, 0);
                }
            }
            // gates + comm stores
#pragma unroll
            for (int ct = 0; ct < 2; ++ct)
#pragma unroll
                for (int i = 0; i < 4; ++i) {
                    int b = drow0 + i;
                    float z = 1.f / (1.f + exp2f(-1.4426950408889634f * (az[ct][i] + bz[ct])));
                    st_cc_f32(&zbuf[b * NU + colz[ct]], z);
                    float r = 1.f / (1.f + exp2f(-1.4426950408889634f * (ar[ct][i] + br[ct])));
                    union { unsigned short u; f16 h; } cv; cv.u = (unsigned short)hs[ct * 4 + i];
                    union { f16 h; unsigned short u; } cw; cw.h = (f16)(r * (float)cv.h);
                    st_cc_u16(&rh16[b * NU + colz[ct]], (unsigned)cw.u);
                }
            asm volatile("s_waitcnt vmcnt(0)" ::: "memory");
            __syncthreads();
            if (tid == 0) st_cc_i32(&aflags[wg], t + 1);
        }
    } else {
        // ---------------- B role: hh + state update, 64 cols ----------------
        const int j = wg - NA, chb = j * 64;
        float bh[4];
        int colh[4];
        const f16* kh[4];
#pragma unroll
        for (int ct = 0; ct < 4; ++ct) {
            int gc = chb + ct * 16 + c16;
            colh[ct] = gc;
            bh[ct] = bias[2048 + gc];
            kh[ct] = kwT + (size_t)(2048 + gc) * NE + aoff;
        }
        float hprev[4][4];
#pragma unroll
        for (int ct = 0; ct < 4; ++ct)
#pragma unroll
            for (int i = 0; i < 4; ++i)
                hprev[ct][i] = hid[(size_t)(drow0 + i) * NU + colh[ct]];

        for (int t = 0; t < NTIME; ++t) {
            f32x4 ah[4];
#pragma unroll
            for (int ct = 0; ct < 4; ++ct) ah[ct] = f32x4{0,0,0,0};
            // x-part
            {
                const int xid = x[arow * NTIME + t];
                const float* ep = emb + (size_t)xid * NE + aoff;
                half8 ea[8];
#pragma unroll
                for (int kc = 0; kc < 8; ++kc) ea[kc] = cvt8(ep + kc * 32);
#pragma unroll
                for (int kc = 0; kc < 8; ++kc)
#pragma unroll
                    for (int ct = 0; ct < 4; ++ct)
                        ah[ct] = MFMA16(ea[kc], *(const half8*)(kh[ct] + kc * 32), ah[ct], 0, 0, 0);
            }
            // wait: all A finished step t (z/rh ready; h_t no longer read)
            if (tid < 64) {
                for (;;) {
                    int v = __hip_atomic_load(&aflags[lane & 31], __ATOMIC_RELAXED, __HIP_MEMORY_SCOPE_AGENT);
                    if (__all(v >= t + 1)) break;
                    __builtin_amdgcn_s_sleep(1);
                }
            }
            __syncthreads();
            __builtin_amdgcn_sched_barrier(0);

            const f16* rp = rh16 + arow * NU + aoff;
            half8 ra[32];
#pragma unroll
            for (int kc = 0; kc < 32; ++kc) ra[kc] = ld_cc_b128(rp + kc * 32);
            float zz[4][4];
#pragma unroll
            for (int ct = 0; ct < 4; ++ct)
#pragma unroll
                for (int i = 0; i < 4; ++i)
                    zz[ct][i] = ld_cc_f32(&zbuf[(size_t)(drow0 + i) * NU + colh[ct]]);
            drain_vm();
            // recurrent MFMA: B-operands from LDS (Wh @0)
#pragma unroll
            for (int kc = 0; kc < 32; ++kc) {
                int kb = ((kc * 32 + aoff) * 2) ^ swz;
#pragma unroll
                for (int ct = 0; ct < 4; ++ct)
                    ah[ct] = MFMA16(ra[kc], *(const half8*)(lds + (ct * 16 + c16) * 2048 + kb), ah[ct], 0, 0, 0);
            }
            // state update + h store (comm)
#pragma unroll
            for (int ct = 0; ct < 4; ++ct)
#pragma unroll
                for (int i = 0; i < 4; ++i) {
                    int b = drow0 + i;
                    float s = ah[ct][i] + bh[ct];
                    float e = exp2f(2.8853900817779268f * s);
                    float hh = 1.f - 2.f / (e + 1.f);          // tanh(s), inf-safe
                    float hn = zz[ct][i] * hprev[ct][i] + (1.f - zz[ct][i]) * hh;
                    hprev[ct][i] = hn;
                    union { f16 h; unsigned short u; } cw; cw.h = (f16)hn;
                    st_cc_u16(&hf16[b * NU + colh[ct]], (unsigned)cw.u);
                }
            asm volatile("s_waitcnt vmcnt(0)" ::: "memory");
            __syncthreads();
            if (tid == 0) st_cc_i32(&bflags[j], t + 1);
            // out stores AFTER the flag — acks overlap the A-phase
#pragma unroll
            for (int ct = 0; ct < 4; ++ct)
#pragma unroll
                for (int i = 0; i < 4; ++i) {
                    int b = drow0 + i;
                    __builtin_nontemporal_store(hprev[ct][i],
                        &out[(size_t)b * (NTIME * NU) + (size_t)t * NU + colh[ct]]);
                }
            if (t == NTIME - 1) {
#pragma unroll
                for (int ct = 0; ct < 4; ++ct)
#pragma unroll
                    for (int i = 0; i < 4; ++i)
                        __builtin_nontemporal_store(hprev[ct][i],
                            &out[(size_t)NBATCH * NTIME * NU + (drow0 + i) * NU + colh[ct]]);
            }
        }
    }
}

extern "C" void kernel_launch(void* const* d_in, const int* in_sizes, int n_in,
                              void* d_out, int out_size, void* d_ws, size_t ws_size,
                              hipStream_t stream)
{
    const int*   x    = (const int*)d_in[0];
    const float* hid  = (const float*)d_in[1];
    const float* emb  = (const float*)d_in[2];
    const float* kw   = (const float*)d_in[3];
    const float* rk   = (const float*)d_in[4];
    const float* bias = (const float*)d_in[5];

    char* ws = (char*)d_ws;
    f16*   kwT   = (f16*)  (ws + OFF_KWT);
    f16*   hf16  = (f16*)  (ws + OFF_HF16);
    f16*   rh16  = (f16*)  (ws + OFF_RH16);
    float* zbuf  = (float*)(ws + OFF_ZBUF);
    int*   flags = (int*)  (ws + OFF_FLAGS);
    float* out   = (float*)d_out;

    prep_kernel<<<64, 256, 0, stream>>>(hid, hf16, flags);
    transpose_kernel<<<dim3(48, 4), 256, 0, stream>>>(kw, kwT, NE);   // kw: 256 x 3072
    scan_kernel<<<NA + NB, 256, 0, stream>>>(x, rk, bias, emb, kwT, hid,
                                             hf16, rh16, zbuf, flags, out);
}